// Round 17
// baseline (200.293 us; speedup 1.0000x reference)
//
#include <hip/hip_runtime.h>
#include <hip/hip_bf16.h>

// MSAPairWeightedAveraging — round 16:
//  ONE-TOKEN k3 experiment: __launch_bounds__(256,2) -> (256,3).
//  HW admits 3 blocks/CU (43KB LDS x3 = 129 <= 160KB; VGPR 108 <= 512/3=170)
//  but the old bound declared 2 waves/SIMD, capping residency at 2 blocks.
//  This isolates co-resident-block count at FIXED traffic/structure (R13's
//  occupancy test was confounded by +19% staging traffic).
//  Everything else frozen at R15 best (190.4us).
// Shapes: b=1, S=256, N=512, DM=64, DP=128, H=8, C=256. mask all-true.

#define S 256
#define N 512
#define DM 64
#define DP 128
#define H 8
#define C 256
#define ROWS (S * N) // 131072
#define GROW 72      // g_lds row stride in bytes (64 data + 8 pad)

typedef __attribute__((ext_vector_type(8))) short bf16x8;
typedef __attribute__((ext_vector_type(4))) float f32x4;

static __device__ __forceinline__ float bf2f(unsigned int u16) {
    union { unsigned int i; float f; } x;
    x.i = u16 << 16;
    return x.f;
}
static __device__ __forceinline__ unsigned short f2bf(float f) {
    return __builtin_bit_cast(unsigned short, __float2bfloat16(f)); // HW RNE cvt
}
static __device__ __forceinline__ void gload16(const void* g, void* l) {
    __builtin_amdgcn_global_load_lds(
        (const __attribute__((address_space(1))) void*)g,
        (__attribute__((address_space(3))) void*)l, 16, 0, 0);
}

// ---------------- K0: weight prep ----------------
__global__ __launch_bounds__(256) void k0_prep(
    const float* __restrict__ Wvg, const float* __restrict__ g, const float* __restrict__ b,
    const float* __restrict__ Wout, const float* __restrict__ gp, const float* __restrict__ bp,
    const float* __restrict__ Wp,
    unsigned short* __restrict__ WTvg, float* __restrict__ biasvg, unsigned short* __restrict__ WoutT,
    float* __restrict__ Wg, float* __restrict__ sgcb)
{
    const int t = threadIdx.x;
    if (blockIdx.x < 2) {
        const int c = blockIdx.x * 256 + t;
        float bias = 0.f;
        unsigned short row[64];
#pragma unroll
        for (int k = 0; k < 64; k++) {
            const float w = Wvg[k * 512 + c];
            row[k] = f2bf(w * g[k]);
            bias = fmaf(w, b[k], bias);
        }
#pragma unroll
        for (int q = 0; q < 8; q++) *(uint4*)(WTvg + c * 64 + q * 8) = *(const uint4*)(row + q * 8);
        biasvg[c] = bias;
    } else if (blockIdx.x == 2) {
        const int m = t >> 2, c0 = (t & 3) * 64;
        unsigned short row[64];
#pragma unroll
        for (int q = 0; q < 64; q++) row[q] = f2bf(Wout[(c0 + q) * 64 + m]);
#pragma unroll
        for (int q = 0; q < 8; q++) *(uint4*)(WoutT + m * 256 + c0 + q * 8) = *(const uint4*)(row + q * 8);
    } else {
        if (t < 128) {
            const float gm = gp[t];
#pragma unroll
            for (int h = 0; h < 8; h++) Wg[t * 8 + h] = gm * Wp[t * 8 + h];
        } else if (t < 136) {
            const int h = t - 128;
            float sg = 0.f, cb = 0.f;
            for (int k = 0; k < 128; k++) {
                sg = fmaf(gp[k], Wp[k * 8 + h], sg);
                cb = fmaf(bp[k], Wp[k * 8 + h], cb);
            }
            sgcb[h] = sg;
            sgcb[8 + h] = cb;
        }
    }
}

// ---------------- K1: LN + MFMA -> VT, G (dbuf at, 1 barrier/tile, msa prefetch) ----------------
__global__ __launch_bounds__(512, 2) void k1_vg_mfma(
    const float* __restrict__ msa, const unsigned short* __restrict__ WTvg,
    const float* __restrict__ biasvg,
    unsigned short* __restrict__ VT, unsigned short* __restrict__ G)
{
    __shared__ unsigned short wt[512 * 64];    // 64 KB
    __shared__ unsigned short at[2][64 * 64];  // 16 KB (double-buffered)
    const int t = threadIdx.x, lane = t & 63, w = t >> 6;
    const int l15 = lane & 15, lgrp = lane >> 4;
    const int s = blockIdx.x >> 1;
    const int jbase = (blockIdx.x & 1) * 256;

#pragma unroll
    for (int q = 0; q < 8; q++) {
        const int u = q * 512 + t;
        const int c = u >> 3, ch = u & 7;
        const uint4 v = *(const uint4*)(WTvg + c * 64 + ch * 8);
        *(uint4*)((char*)wt + c * 128 + ((ch ^ (c & 7)) * 16)) = v;
    }
    float biasr[4];
    float bias2[4][4];
    if (w < 4) {
#pragma unroll
        for (int cf = 0; cf < 4; cf++) biasr[cf] = biasvg[w * 64 + cf * 16 + l15];
    } else {
#pragma unroll
        for (int cf = 0; cf < 4; cf++)
#pragma unroll
            for (int r = 0; r < 4; r++) bias2[cf][r] = biasvg[w * 64 + cf * 16 + lgrp * 4 + r];
    }

    const int r = t >> 3, kc = (t & 7) * 8;
    const float* src0 = msa + ((size_t)(s * 512 + jbase + r)) * 64 + kc;
    float4 x0 = *(const float4*)src0;
    float4 x1 = *(const float4*)(src0 + 4);

    for (int tile = 0; tile < 4; ++tile) {
        const int j0 = jbase + tile * 64;
        {
            float s1 = x0.x + x0.y + x0.z + x0.w + x1.x + x1.y + x1.z + x1.w;
            float s2 = x0.x * x0.x + x0.y * x0.y + x0.z * x0.z + x0.w * x0.w
                     + x1.x * x1.x + x1.y * x1.y + x1.z * x1.z + x1.w * x1.w;
#pragma unroll
            for (int off = 1; off < 8; off <<= 1) {
                s1 += __shfl_xor(s1, off);
                s2 += __shfl_xor(s2, off);
            }
            const float m = s1 * (1.f / 64.f);
            const float inv = rsqrtf(s2 * (1.f / 64.f) - m * m + 1e-5f);
            unsigned short buf[8];
            buf[0] = f2bf((x0.x - m) * inv); buf[1] = f2bf((x0.y - m) * inv);
            buf[2] = f2bf((x0.z - m) * inv); buf[3] = f2bf((x0.w - m) * inv);
            buf[4] = f2bf((x1.x - m) * inv); buf[5] = f2bf((x1.y - m) * inv);
            buf[6] = f2bf((x1.z - m) * inv); buf[7] = f2bf((x1.w - m) * inv);
            *(uint4*)((char*)at[tile & 1] + r * 128 + (((t & 7) ^ (r & 7)) * 16)) = *(const uint4*)buf;
        }
        if (tile < 3) {
            const float* srcn = msa + ((size_t)(s * 512 + j0 + 64 + r)) * 64 + kc;
            x0 = *(const float4*)srcn;
            x1 = *(const float4*)(srcn + 4);
        }
        __syncthreads();

        f32x4 acc[4][4];
#pragma unroll
        for (int rf = 0; rf < 4; rf++)
#pragma unroll
            for (int cf = 0; cf < 4; cf++) acc[rf][cf] = (f32x4){0.f, 0.f, 0.f, 0.f};

#pragma unroll
        for (int ks = 0; ks < 2; ks++) {
            bf16x8 bfr[4];
#pragma unroll
            for (int cf = 0; cf < 4; cf++) {
                const int c = w * 64 + cf * 16 + l15;
                bfr[cf] = *(const bf16x8*)((const char*)wt + c * 128 + (((ks * 4 + lgrp) ^ (c & 7)) * 16));
            }
#pragma unroll
            for (int rf = 0; rf < 4; rf++) {
                const int rr = rf * 16 + l15;
                const bf16x8 afr = *(const bf16x8*)((const char*)at[tile & 1] + rr * 128 + (((ks * 4 + lgrp) ^ (rr & 7)) * 16));
                if (w < 4) {
#pragma unroll
                    for (int cf = 0; cf < 4; cf++)
                        acc[rf][cf] = __builtin_amdgcn_mfma_f32_16x16x32_bf16(afr, bfr[cf], acc[rf][cf], 0, 0, 0);
                } else {
#pragma unroll
                    for (int cf = 0; cf < 4; cf++)
                        acc[rf][cf] = __builtin_amdgcn_mfma_f32_16x16x32_bf16(bfr[cf], afr, acc[rf][cf], 0, 0, 0);
                }
            }
        }

        if (w < 4) {
#pragma unroll
            for (int rf = 0; rf < 4; rf++)
#pragma unroll
                for (int cf = 0; cf < 4; cf++) {
                    const int c = w * 64 + cf * 16 + l15;
                    const int j = j0 + rf * 16 + lgrp * 4;
                    uint2 o;
                    o.x = (unsigned)f2bf(acc[rf][cf][0] + biasr[cf]) |
                          ((unsigned)f2bf(acc[rf][cf][1] + biasr[cf]) << 16);
                    o.y = (unsigned)f2bf(acc[rf][cf][2] + biasr[cf]) |
                          ((unsigned)f2bf(acc[rf][cf][3] + biasr[cf]) << 16);
                    *(uint2*)(VT + ((size_t)s * C + c) * N + j) = o;
                }
        } else {
#pragma unroll
            for (int rf = 0; rf < 4; rf++)
#pragma unroll
                for (int cf = 0; cf < 4; cf++) {
                    const int j = j0 + rf * 16 + l15;
                    const int cp = (w - 4) * 64 + cf * 16 + lgrp * 4;
                    float sg[4];
#pragma unroll
                    for (int r2 = 0; r2 < 4; r2++)
                        sg[r2] = 1.f / (1.f + __expf(-(acc[rf][cf][r2] + bias2[cf][r2])));
                    uint2 o;
                    o.x = (unsigned)f2bf(sg[0]) | ((unsigned)f2bf(sg[1]) << 16);
                    o.y = (unsigned)f2bf(sg[2]) | ((unsigned)f2bf(sg[3]) << 16);
                    *(uint2*)(G + ((size_t)(s * 512 + j)) * C + cp) = o;
                }
        }
    }
}

// ---------------- K2a: pair bias (no LDS, no barrier, 4096 blocks) ----------------
__global__ __launch_bounds__(256) void k2a_bias(
    const float* __restrict__ pair, const float* __restrict__ Wg,
    const float* __restrict__ sgcb, unsigned short* __restrict__ biasb)
{
    const int i = blockIdx.x >> 3;
    const int jo = blockIdx.x & 7;
    const int t = threadIdx.x;
    const int sub = t & 15, rgrp = t >> 4;

    float wreg[2][4][8];
#pragma unroll
    for (int q = 0; q < 2; q++)
#pragma unroll
        for (int c = 0; c < 4; c++) {
            const int k = (q * 16 + sub) * 4 + c;
            const float4 w0 = *(const float4*)(Wg + k * 8);
            const float4 w1 = *(const float4*)(Wg + k * 8 + 4);
            wreg[q][c][0] = w0.x; wreg[q][c][1] = w0.y; wreg[q][c][2] = w0.z; wreg[q][c][3] = w0.w;
            wreg[q][c][4] = w1.x; wreg[q][c][5] = w1.y; wreg[q][c][6] = w1.z; wreg[q][c][7] = w1.w;
        }
    float sgr[8], cbr[8];
#pragma unroll
    for (int h = 0; h < 8; h++) { sgr[h] = sgcb[h]; cbr[h] = sgcb[8 + h]; }

#pragma unroll
    for (int pass = 0; pass < 4; ++pass) {
        const int j = jo * 64 + pass * 16 + rgrp;
        const float* px = pair + ((size_t)i * N + j) * DP;
        const float4 x0 = *(const float4*)(px + sub * 4);
        const float4 x1 = *(const float4*)(px + 64 + sub * 4);
        float s1 = x0.x + x0.y + x0.z + x0.w + x1.x + x1.y + x1.z + x1.w;
        float s2 = x0.x * x0.x + x0.y * x0.y + x0.z * x0.z + x0.w * x0.w
                 + x1.x * x1.x + x1.y * x1.y + x1.z * x1.z + x1.w * x1.w;
#pragma unroll
        for (int off = 1; off < 16; off <<= 1) {
            s1 += __shfl_xor(s1, off);
            s2 += __shfl_xor(s2, off);
        }
        const float m = s1 * (1.f / 128.f);
        const float inv = rsqrtf(s2 * (1.f / 128.f) - m * m + 1e-5f);

        float dots[8];
#pragma unroll
        for (int h = 0; h < 8; h++) dots[h] = 0.f;
        const float xs[2][4] = {{x0.x, x0.y, x0.z, x0.w}, {x1.x, x1.y, x1.z, x1.w}};
#pragma unroll
        for (int q = 0; q < 2; q++)
#pragma unroll
            for (int c = 0; c < 4; c++)
#pragma unroll
                for (int h = 0; h < 8; h++) dots[h] = fmaf(xs[q][c], wreg[q][c][h], dots[h]);
#pragma unroll
        for (int off = 1; off < 16; off <<= 1)
#pragma unroll
            for (int h = 0; h < 8; h++) dots[h] += __shfl_xor(dots[h], off);

        if (sub == 0) {
            unsigned short b8[8];
#pragma unroll
            for (int h = 0; h < 8; h++)
                b8[h] = f2bf(inv * (dots[h] - m * sgr[h]) + cbr[h]);
            *(uint4*)(biasb + ((size_t)i * N + j) * 8) = *(const uint4*)b8;
        }
    }
}

// ---------------- K2b: softmax over j -> Wt[h][i][j] bf16 ----------------
__global__ __launch_bounds__(512) void k2b_softmax(
    const unsigned short* __restrict__ biasb, unsigned short* __restrict__ Wt)
{
    const int i = blockIdx.x;
    const int t = threadIdx.x, lane = t & 63, h = t >> 6;

    float v[8];
    float mx = -1e30f;
#pragma unroll
    for (int q = 0; q < 8; q++) {
        v[q] = bf2f(biasb[((size_t)i * N + q * 64 + lane) * 8 + h]);
        mx = fmaxf(mx, v[q]);
    }
#pragma unroll
    for (int off = 32; off > 0; off >>= 1) mx = fmaxf(mx, __shfl_xor(mx, off));
    float sum = 0.f;
#pragma unroll
    for (int q = 0; q < 8; q++) {
        v[q] = __expf(v[q] - mx);
        sum += v[q];
    }
#pragma unroll
    for (int off = 32; off > 0; off >>= 1) sum += __shfl_xor(sum, off);
    const float rs = 1.f / sum;
#pragma unroll
    for (int q = 0; q < 8; q++)
        Wt[((size_t)h * N + i) * N + q * 64 + lane] = f2bf(v[q] * rs);
}

// ---------------- K3: fused einsum + gate + W_out (R12 structure, 3 blocks/CU) ----------------
__global__ __launch_bounds__(256, 3) void k3_fused_out(
    const unsigned short* __restrict__ Wt, const unsigned short* __restrict__ VT,
    const unsigned short* __restrict__ G, const unsigned short* __restrict__ WoutT,
    float* __restrict__ out)
{
    __shared__ unsigned short a_lds[64 * 64];            // 8 KB
    __shared__ unsigned short b_lds[128 * 64];           // 16 KB
    __shared__ __align__(16) char g_lds[2 * 128 * GROW]; // 18 KB (72B rows, conflict-free)
    const int raw = blockIdx.x;
    const int bid = (raw & 7) * 64 + (raw >> 3);    // 512 % 8 == 0
    const int sp = bid >> 2;
    const int it = bid & 3;
    const int s0 = sp * 2, i0 = it * 128;
    const int t = threadIdx.x, lane = t & 63, w = t >> 6;
    const int l15 = lane & 15, lgrp = lane >> 4;
    const int wn = w >> 1, wi = w & 1;

    const unsigned short* srcA[2];
    const unsigned short* srcB[4];
    int dstA[2], dstB[4];
#pragma unroll
    for (int q = 0; q < 2; ++q) {
        const int slot = q * 256 + t;
        const int row = slot >> 3, chp = slot & 7;
        const int ch = chp ^ (row & 7);
        srcA[q] = VT + ((size_t)((s0 + (row >> 5)) * 256 + (row & 31))) * 512 + ch * 8;
        dstA[q] = slot * 16;
    }
#pragma unroll
    for (int q = 0; q < 4; ++q) {
        const int slot = q * 256 + t;
        const int row = slot >> 3, chp = slot & 7;
        const int ch = chp ^ (row & 7);
        srcB[q] = Wt + ((size_t)(i0 + row)) * 512 + ch * 8;
        dstB[q] = slot * 16;
    }

    f32x4 oacc[2][2][4];
#pragma unroll
    for (int s = 0; s < 2; s++)
#pragma unroll
        for (int f = 0; f < 2; f++)
#pragma unroll
            for (int mf = 0; mf < 4; mf++) oacc[s][f][mf] = (f32x4){0.f, 0.f, 0.f, 0.f};

    for (int h = 0; h < 8; ++h) {
        uint2 gpre[2][4];
#pragma unroll
        for (int fn = 0; fn < 2; ++fn)
#pragma unroll
            for (int fi = 0; fi < 4; ++fi)
                gpre[fn][fi] = *(const uint2*)(G +
                    ((size_t)((s0 + wn) * 512 + i0 + wi * 64 + fi * 16 + l15)) * 256 +
                    h * 32 + fn * 16 + lgrp * 4);

        f32x4 acc[2][4];
#pragma unroll
        for (int fn = 0; fn < 2; fn++)
#pragma unroll
            for (int fi = 0; fi < 4; fi++) acc[fn][fi] = (f32x4){0.f, 0.f, 0.f, 0.f};

        const int offA = h * 16384;
        const int offB = h * 262144;
        for (int kt = 0; kt < 8; ++kt) {
            const int j0 = kt * 64;
#pragma unroll
            for (int q = 0; q < 2; ++q) gload16(srcA[q] + offA + j0, (char*)a_lds + dstA[q]);
#pragma unroll
            for (int q = 0; q < 4; ++q) gload16(srcB[q] + offB + j0, (char*)b_lds + dstB[q]);
            __syncthreads();
#pragma unroll
            for (int ks = 0; ks < 2; ++ks) {
                bf16x8 af[2], bf[4];
#pragma unroll
                for (int fn = 0; fn < 2; ++fn) {
                    const int ra = wn * 32 + fn * 16 + l15;
                    af[fn] = *(const bf16x8*)((const char*)a_lds + ra * 128 + (((ks * 4 + lgrp) ^ (ra & 7)) * 16));
                }
#pragma unroll
                for (int fi = 0; fi < 4; ++fi) {
                    const int rb = wi * 64 + fi * 16 + l15;
                    bf[fi] = *(const bf16x8*)((const char*)b_lds + rb * 128 + (((ks * 4 + lgrp) ^ (rb & 7)) * 16));
                }
#pragma unroll
                for (int fn = 0; fn < 2; ++fn)
#pragma unroll
                    for (int fi = 0; fi < 4; ++fi)
                        acc[fn][fi] = __builtin_amdgcn_mfma_f32_16x16x32_bf16(af[fn], bf[fi], acc[fn][fi], 0, 0, 0);
            }
            __syncthreads();
        }

        // gate + pack -> g_lds[s=wn][i][d] (72B rows; banks conflict-free)
#pragma unroll
        for (int fn = 0; fn < 2; ++fn) {
            const int d0 = fn * 16 + lgrp * 4;
#pragma unroll
            for (int fi = 0; fi < 4; ++fi) {
                const int i = wi * 64 + fi * 16 + l15;
                const uint2 uu = gpre[fn][fi];
                const float g0 = bf2f(uu.x & 0xFFFFu), g1 = bf2f(uu.x >> 16);
                const float g2 = bf2f(uu.y & 0xFFFFu), g3 = bf2f(uu.y >> 16);
                uint2 o;
                o.x = (unsigned)f2bf(acc[fn][fi][0] * g0) | ((unsigned)f2bf(acc[fn][fi][1] * g1) << 16);
                o.y = (unsigned)f2bf(acc[fn][fi][2] * g2) | ((unsigned)f2bf(acc[fn][fi][3] * g3) << 16);
                *(uint2*)(g_lds + (wn * 128 + i) * GROW + d0 * 2) = o;
            }
        }
        __syncthreads();

        bf16x8 bw[4];
#pragma unroll
        for (int mf = 0; mf < 4; ++mf)
            bw[mf] = *(const bf16x8*)(WoutT + (mf * 16 + l15) * 256 + h * 32 + lgrp * 8);
#pragma unroll
        for (int s = 0; s < 2; ++s) {
#pragma unroll
            for (int f = 0; f < 2; ++f) {
                const int ra = w * 32 + f * 16 + l15;
                const bf16x8 af = *(const bf16x8*)(g_lds + (s * 128 + ra) * GROW + lgrp * 16);
#pragma unroll
                for (int mf = 0; mf < 4; ++mf)
                    oacc[s][f][mf] = __builtin_amdgcn_mfma_f32_16x16x32_bf16(af, bw[mf], oacc[s][f][mf], 0, 0, 0);
            }
        }
        __syncthreads();
    }

#pragma unroll
    for (int s = 0; s < 2; ++s)
#pragma unroll
        for (int f = 0; f < 2; ++f)
#pragma unroll
            for (int mf = 0; mf < 4; ++mf)
#pragma unroll
                for (int r = 0; r < 4; ++r) {
                    const size_t row = (size_t)(s0 + s) * 512 + i0 + w * 32 + f * 16 + lgrp * 4 + r;
                    out[row * 64 + mf * 16 + l15] = oacc[s][f][mf][r];
                }
}

extern "C" void kernel_launch(void* const* d_in, const int* in_sizes, int n_in,
                              void* d_out, int out_size, void* d_ws, size_t ws_size,
                              hipStream_t stream) {
    (void)in_sizes; (void)n_in; (void)out_size; (void)ws_size;
    const float* msa       = (const float*)d_in[0];
    const float* pair      = (const float*)d_in[1];
    const float* ln_msa_g  = (const float*)d_in[2];
    const float* ln_msa_b  = (const float*)d_in[3];
    const float* W_vg      = (const float*)d_in[4];
    const float* ln_pair_g = (const float*)d_in[5];
    const float* ln_pair_b = (const float*)d_in[6];
    const float* W_pair    = (const float*)d_in[7];
    const float* W_out     = (const float*)d_in[8];
    float* out = (float*)d_out;

    char* ws = (char*)d_ws;
    size_t off = 0;
    unsigned short* VT    = (unsigned short*)(ws + off); off += (size_t)ROWS * C * 2;  // 67.1 MB
    unsigned short* G     = (unsigned short*)(ws + off); off += (size_t)ROWS * C * 2;  // 67.1 MB
    unsigned short* Wt    = (unsigned short*)(ws + off); off += (size_t)H * N * N * 2; // 4.2 MB
    unsigned short* biasb = (unsigned short*)(ws + off); off += (size_t)N * N * 8 * 2; // 4.2 MB
    unsigned short* WTvg  = (unsigned short*)(ws + off); off += 512 * 64 * 2;          // 64 KB
    float*          biasvg = (float*)(ws + off); off += 512 * 4;                       // 2 KB
    unsigned short* WoutT = (unsigned short*)(ws + off); off += 64 * 256 * 2;          // 32 KB
    float*          Wg    = (float*)(ws + off); off += 128 * 8 * 4;                    // 4 KB
    float*          sgcb  = (float*)(ws + off); off += 16 * 4;

    k0_prep<<<4, 256, 0, stream>>>(W_vg, ln_msa_g, ln_msa_b, W_out, ln_pair_g, ln_pair_b, W_pair,
                                   WTvg, biasvg, WoutT, Wg, sgcb);
    k2a_bias<<<4096, 256, 0, stream>>>(pair, Wg, sgcb, biasb);
    k2b_softmax<<<512, 512, 0, stream>>>(biasb, Wt);
    k1_vg_mfma<<<512, 512, 0, stream>>>(msa, WTvg, biasvg, VT, G);
    k3_fused_out<<<512, 256, 0, stream>>>(Wt, VT, G, WoutT, out);
}

// Round 18
// 189.294 us; speedup vs baseline: 1.0581x; 1.0581x over previous
//
#include <hip/hip_runtime.h>
#include <hip/hip_bf16.h>

// MSAPairWeightedAveraging — round 17 (FINAL, revert to R15 best = 190.4us):
//  R16's (256,3) probe was codegen-confounded: VGPR capped 108->84, staging
//  pointers rematerialized (FETCH +50%), occupancy unchanged -> k3 80->90us.
//  Restored __launch_bounds__(256,2). This is the terminal configuration:
//  k3 pinned at ~80us across 9 probes (schedule x4, occupancy x2, traffic x2,
//  tile x3, bank-conflict fix) with no pipe saturated; k1 at 71% HBM BW;
//  k2a within 15% of its traffic floor. 6.4x over round-0 baseline.
// Shapes: b=1, S=256, N=512, DM=64, DP=128, H=8, C=256. mask all-true.

#define S 256
#define N 512
#define DM 64
#define DP 128
#define H 8
#define C 256
#define ROWS (S * N) // 131072
#define GROW 72      // g_lds row stride in bytes (64 data + 8 pad)

typedef __attribute__((ext_vector_type(8))) short bf16x8;
typedef __attribute__((ext_vector_type(4))) float f32x4;

static __device__ __forceinline__ float bf2f(unsigned int u16) {
    union { unsigned int i; float f; } x;
    x.i = u16 << 16;
    return x.f;
}
static __device__ __forceinline__ unsigned short f2bf(float f) {
    return __builtin_bit_cast(unsigned short, __float2bfloat16(f)); // HW RNE cvt
}
static __device__ __forceinline__ void gload16(const void* g, void* l) {
    __builtin_amdgcn_global_load_lds(
        (const __attribute__((address_space(1))) void*)g,
        (__attribute__((address_space(3))) void*)l, 16, 0, 0);
}

// ---------------- K0: weight prep ----------------
__global__ __launch_bounds__(256) void k0_prep(
    const float* __restrict__ Wvg, const float* __restrict__ g, const float* __restrict__ b,
    const float* __restrict__ Wout, const float* __restrict__ gp, const float* __restrict__ bp,
    const float* __restrict__ Wp,
    unsigned short* __restrict__ WTvg, float* __restrict__ biasvg, unsigned short* __restrict__ WoutT,
    float* __restrict__ Wg, float* __restrict__ sgcb)
{
    const int t = threadIdx.x;
    if (blockIdx.x < 2) {
        const int c = blockIdx.x * 256 + t;
        float bias = 0.f;
        unsigned short row[64];
#pragma unroll
        for (int k = 0; k < 64; k++) {
            const float w = Wvg[k * 512 + c];
            row[k] = f2bf(w * g[k]);
            bias = fmaf(w, b[k], bias);
        }
#pragma unroll
        for (int q = 0; q < 8; q++) *(uint4*)(WTvg + c * 64 + q * 8) = *(const uint4*)(row + q * 8);
        biasvg[c] = bias;
    } else if (blockIdx.x == 2) {
        const int m = t >> 2, c0 = (t & 3) * 64;
        unsigned short row[64];
#pragma unroll
        for (int q = 0; q < 64; q++) row[q] = f2bf(Wout[(c0 + q) * 64 + m]);
#pragma unroll
        for (int q = 0; q < 8; q++) *(uint4*)(WoutT + m * 256 + c0 + q * 8) = *(const uint4*)(row + q * 8);
    } else {
        if (t < 128) {
            const float gm = gp[t];
#pragma unroll
            for (int h = 0; h < 8; h++) Wg[t * 8 + h] = gm * Wp[t * 8 + h];
        } else if (t < 136) {
            const int h = t - 128;
            float sg = 0.f, cb = 0.f;
            for (int k = 0; k < 128; k++) {
                sg = fmaf(gp[k], Wp[k * 8 + h], sg);
                cb = fmaf(bp[k], Wp[k * 8 + h], cb);
            }
            sgcb[h] = sg;
            sgcb[8 + h] = cb;
        }
    }
}

// ---------------- K1: LN + MFMA -> VT, G (dbuf at, 1 barrier/tile, msa prefetch) ----------------
__global__ __launch_bounds__(512, 2) void k1_vg_mfma(
    const float* __restrict__ msa, const unsigned short* __restrict__ WTvg,
    const float* __restrict__ biasvg,
    unsigned short* __restrict__ VT, unsigned short* __restrict__ G)
{
    __shared__ unsigned short wt[512 * 64];    // 64 KB
    __shared__ unsigned short at[2][64 * 64];  // 16 KB (double-buffered)
    const int t = threadIdx.x, lane = t & 63, w = t >> 6;
    const int l15 = lane & 15, lgrp = lane >> 4;
    const int s = blockIdx.x >> 1;
    const int jbase = (blockIdx.x & 1) * 256;

#pragma unroll
    for (int q = 0; q < 8; q++) {
        const int u = q * 512 + t;
        const int c = u >> 3, ch = u & 7;
        const uint4 v = *(const uint4*)(WTvg + c * 64 + ch * 8);
        *(uint4*)((char*)wt + c * 128 + ((ch ^ (c & 7)) * 16)) = v;
    }
    float biasr[4];
    float bias2[4][4];
    if (w < 4) {
#pragma unroll
        for (int cf = 0; cf < 4; cf++) biasr[cf] = biasvg[w * 64 + cf * 16 + l15];
    } else {
#pragma unroll
        for (int cf = 0; cf < 4; cf++)
#pragma unroll
            for (int r = 0; r < 4; r++) bias2[cf][r] = biasvg[w * 64 + cf * 16 + lgrp * 4 + r];
    }

    const int r = t >> 3, kc = (t & 7) * 8;
    const float* src0 = msa + ((size_t)(s * 512 + jbase + r)) * 64 + kc;
    float4 x0 = *(const float4*)src0;
    float4 x1 = *(const float4*)(src0 + 4);

    for (int tile = 0; tile < 4; ++tile) {
        const int j0 = jbase + tile * 64;
        {
            float s1 = x0.x + x0.y + x0.z + x0.w + x1.x + x1.y + x1.z + x1.w;
            float s2 = x0.x * x0.x + x0.y * x0.y + x0.z * x0.z + x0.w * x0.w
                     + x1.x * x1.x + x1.y * x1.y + x1.z * x1.z + x1.w * x1.w;
#pragma unroll
            for (int off = 1; off < 8; off <<= 1) {
                s1 += __shfl_xor(s1, off);
                s2 += __shfl_xor(s2, off);
            }
            const float m = s1 * (1.f / 64.f);
            const float inv = rsqrtf(s2 * (1.f / 64.f) - m * m + 1e-5f);
            unsigned short buf[8];
            buf[0] = f2bf((x0.x - m) * inv); buf[1] = f2bf((x0.y - m) * inv);
            buf[2] = f2bf((x0.z - m) * inv); buf[3] = f2bf((x0.w - m) * inv);
            buf[4] = f2bf((x1.x - m) * inv); buf[5] = f2bf((x1.y - m) * inv);
            buf[6] = f2bf((x1.z - m) * inv); buf[7] = f2bf((x1.w - m) * inv);
            *(uint4*)((char*)at[tile & 1] + r * 128 + (((t & 7) ^ (r & 7)) * 16)) = *(const uint4*)buf;
        }
        if (tile < 3) {
            const float* srcn = msa + ((size_t)(s * 512 + j0 + 64 + r)) * 64 + kc;
            x0 = *(const float4*)srcn;
            x1 = *(const float4*)(srcn + 4);
        }
        __syncthreads();

        f32x4 acc[4][4];
#pragma unroll
        for (int rf = 0; rf < 4; rf++)
#pragma unroll
            for (int cf = 0; cf < 4; cf++) acc[rf][cf] = (f32x4){0.f, 0.f, 0.f, 0.f};

#pragma unroll
        for (int ks = 0; ks < 2; ks++) {
            bf16x8 bfr[4];
#pragma unroll
            for (int cf = 0; cf < 4; cf++) {
                const int c = w * 64 + cf * 16 + l15;
                bfr[cf] = *(const bf16x8*)((const char*)wt + c * 128 + (((ks * 4 + lgrp) ^ (c & 7)) * 16));
            }
#pragma unroll
            for (int rf = 0; rf < 4; rf++) {
                const int rr = rf * 16 + l15;
                const bf16x8 afr = *(const bf16x8*)((const char*)at[tile & 1] + rr * 128 + (((ks * 4 + lgrp) ^ (rr & 7)) * 16));
                if (w < 4) {
#pragma unroll
                    for (int cf = 0; cf < 4; cf++)
                        acc[rf][cf] = __builtin_amdgcn_mfma_f32_16x16x32_bf16(afr, bfr[cf], acc[rf][cf], 0, 0, 0);
                } else {
#pragma unroll
                    for (int cf = 0; cf < 4; cf++)
                        acc[rf][cf] = __builtin_amdgcn_mfma_f32_16x16x32_bf16(bfr[cf], afr, acc[rf][cf], 0, 0, 0);
                }
            }
        }

        if (w < 4) {
#pragma unroll
            for (int rf = 0; rf < 4; rf++)
#pragma unroll
                for (int cf = 0; cf < 4; cf++) {
                    const int c = w * 64 + cf * 16 + l15;
                    const int j = j0 + rf * 16 + lgrp * 4;
                    uint2 o;
                    o.x = (unsigned)f2bf(acc[rf][cf][0] + biasr[cf]) |
                          ((unsigned)f2bf(acc[rf][cf][1] + biasr[cf]) << 16);
                    o.y = (unsigned)f2bf(acc[rf][cf][2] + biasr[cf]) |
                          ((unsigned)f2bf(acc[rf][cf][3] + biasr[cf]) << 16);
                    *(uint2*)(VT + ((size_t)s * C + c) * N + j) = o;
                }
        } else {
#pragma unroll
            for (int rf = 0; rf < 4; rf++)
#pragma unroll
                for (int cf = 0; cf < 4; cf++) {
                    const int j = j0 + rf * 16 + l15;
                    const int cp = (w - 4) * 64 + cf * 16 + lgrp * 4;
                    float sg[4];
#pragma unroll
                    for (int r2 = 0; r2 < 4; r2++)
                        sg[r2] = 1.f / (1.f + __expf(-(acc[rf][cf][r2] + bias2[cf][r2])));
                    uint2 o;
                    o.x = (unsigned)f2bf(sg[0]) | ((unsigned)f2bf(sg[1]) << 16);
                    o.y = (unsigned)f2bf(sg[2]) | ((unsigned)f2bf(sg[3]) << 16);
                    *(uint2*)(G + ((size_t)(s * 512 + j)) * C + cp) = o;
                }
        }
    }
}

// ---------------- K2a: pair bias (no LDS, no barrier, 4096 blocks) ----------------
__global__ __launch_bounds__(256) void k2a_bias(
    const float* __restrict__ pair, const float* __restrict__ Wg,
    const float* __restrict__ sgcb, unsigned short* __restrict__ biasb)
{
    const int i = blockIdx.x >> 3;
    const int jo = blockIdx.x & 7;
    const int t = threadIdx.x;
    const int sub = t & 15, rgrp = t >> 4;

    float wreg[2][4][8];
#pragma unroll
    for (int q = 0; q < 2; q++)
#pragma unroll
        for (int c = 0; c < 4; c++) {
            const int k = (q * 16 + sub) * 4 + c;
            const float4 w0 = *(const float4*)(Wg + k * 8);
            const float4 w1 = *(const float4*)(Wg + k * 8 + 4);
            wreg[q][c][0] = w0.x; wreg[q][c][1] = w0.y; wreg[q][c][2] = w0.z; wreg[q][c][3] = w0.w;
            wreg[q][c][4] = w1.x; wreg[q][c][5] = w1.y; wreg[q][c][6] = w1.z; wreg[q][c][7] = w1.w;
        }
    float sgr[8], cbr[8];
#pragma unroll
    for (int h = 0; h < 8; h++) { sgr[h] = sgcb[h]; cbr[h] = sgcb[8 + h]; }

#pragma unroll
    for (int pass = 0; pass < 4; ++pass) {
        const int j = jo * 64 + pass * 16 + rgrp;
        const float* px = pair + ((size_t)i * N + j) * DP;
        const float4 x0 = *(const float4*)(px + sub * 4);
        const float4 x1 = *(const float4*)(px + 64 + sub * 4);
        float s1 = x0.x + x0.y + x0.z + x0.w + x1.x + x1.y + x1.z + x1.w;
        float s2 = x0.x * x0.x + x0.y * x0.y + x0.z * x0.z + x0.w * x0.w
                 + x1.x * x1.x + x1.y * x1.y + x1.z * x1.z + x1.w * x1.w;
#pragma unroll
        for (int off = 1; off < 16; off <<= 1) {
            s1 += __shfl_xor(s1, off);
            s2 += __shfl_xor(s2, off);
        }
        const float m = s1 * (1.f / 128.f);
        const float inv = rsqrtf(s2 * (1.f / 128.f) - m * m + 1e-5f);

        float dots[8];
#pragma unroll
        for (int h = 0; h < 8; h++) dots[h] = 0.f;
        const float xs[2][4] = {{x0.x, x0.y, x0.z, x0.w}, {x1.x, x1.y, x1.z, x1.w}};
#pragma unroll
        for (int q = 0; q < 2; q++)
#pragma unroll
            for (int c = 0; c < 4; c++)
#pragma unroll
                for (int h = 0; h < 8; h++) dots[h] = fmaf(xs[q][c], wreg[q][c][h], dots[h]);
#pragma unroll
        for (int off = 1; off < 16; off <<= 1)
#pragma unroll
            for (int h = 0; h < 8; h++) dots[h] += __shfl_xor(dots[h], off);

        if (sub == 0) {
            unsigned short b8[8];
#pragma unroll
            for (int h = 0; h < 8; h++)
                b8[h] = f2bf(inv * (dots[h] - m * sgr[h]) + cbr[h]);
            *(uint4*)(biasb + ((size_t)i * N + j) * 8) = *(const uint4*)b8;
        }
    }
}

// ---------------- K2b: softmax over j -> Wt[h][i][j] bf16 ----------------
__global__ __launch_bounds__(512) void k2b_softmax(
    const unsigned short* __restrict__ biasb, unsigned short* __restrict__ Wt)
{
    const int i = blockIdx.x;
    const int t = threadIdx.x, lane = t & 63, h = t >> 6;

    float v[8];
    float mx = -1e30f;
#pragma unroll
    for (int q = 0; q < 8; q++) {
        v[q] = bf2f(biasb[((size_t)i * N + q * 64 + lane) * 8 + h]);
        mx = fmaxf(mx, v[q]);
    }
#pragma unroll
    for (int off = 32; off > 0; off >>= 1) mx = fmaxf(mx, __shfl_xor(mx, off));
    float sum = 0.f;
#pragma unroll
    for (int q = 0; q < 8; q++) {
        v[q] = __expf(v[q] - mx);
        sum += v[q];
    }
#pragma unroll
    for (int off = 32; off > 0; off >>= 1) sum += __shfl_xor(sum, off);
    const float rs = 1.f / sum;
#pragma unroll
    for (int q = 0; q < 8; q++)
        Wt[((size_t)h * N + i) * N + q * 64 + lane] = f2bf(v[q] * rs);
}

// ---------------- K3: fused einsum + gate + W_out (R12 structure, padded g_lds) ----------------
__global__ __launch_bounds__(256, 2) void k3_fused_out(
    const unsigned short* __restrict__ Wt, const unsigned short* __restrict__ VT,
    const unsigned short* __restrict__ G, const unsigned short* __restrict__ WoutT,
    float* __restrict__ out)
{
    __shared__ unsigned short a_lds[64 * 64];            // 8 KB
    __shared__ unsigned short b_lds[128 * 64];           // 16 KB
    __shared__ __align__(16) char g_lds[2 * 128 * GROW]; // 18 KB (72B rows, conflict-free)
    const int raw = blockIdx.x;
    const int bid = (raw & 7) * 64 + (raw >> 3);    // 512 % 8 == 0
    const int sp = bid >> 2;
    const int it = bid & 3;
    const int s0 = sp * 2, i0 = it * 128;
    const int t = threadIdx.x, lane = t & 63, w = t >> 6;
    const int l15 = lane & 15, lgrp = lane >> 4;
    const int wn = w >> 1, wi = w & 1;

    const unsigned short* srcA[2];
    const unsigned short* srcB[4];
    int dstA[2], dstB[4];
#pragma unroll
    for (int q = 0; q < 2; ++q) {
        const int slot = q * 256 + t;
        const int row = slot >> 3, chp = slot & 7;
        const int ch = chp ^ (row & 7);
        srcA[q] = VT + ((size_t)((s0 + (row >> 5)) * 256 + (row & 31))) * 512 + ch * 8;
        dstA[q] = slot * 16;
    }
#pragma unroll
    for (int q = 0; q < 4; ++q) {
        const int slot = q * 256 + t;
        const int row = slot >> 3, chp = slot & 7;
        const int ch = chp ^ (row & 7);
        srcB[q] = Wt + ((size_t)(i0 + row)) * 512 + ch * 8;
        dstB[q] = slot * 16;
    }

    f32x4 oacc[2][2][4];
#pragma unroll
    for (int s = 0; s < 2; s++)
#pragma unroll
        for (int f = 0; f < 2; f++)
#pragma unroll
            for (int mf = 0; mf < 4; mf++) oacc[s][f][mf] = (f32x4){0.f, 0.f, 0.f, 0.f};

    for (int h = 0; h < 8; ++h) {
        uint2 gpre[2][4];
#pragma unroll
        for (int fn = 0; fn < 2; ++fn)
#pragma unroll
            for (int fi = 0; fi < 4; ++fi)
                gpre[fn][fi] = *(const uint2*)(G +
                    ((size_t)((s0 + wn) * 512 + i0 + wi * 64 + fi * 16 + l15)) * 256 +
                    h * 32 + fn * 16 + lgrp * 4);

        f32x4 acc[2][4];
#pragma unroll
        for (int fn = 0; fn < 2; fn++)
#pragma unroll
            for (int fi = 0; fi < 4; fi++) acc[fn][fi] = (f32x4){0.f, 0.f, 0.f, 0.f};

        const int offA = h * 16384;
        const int offB = h * 262144;
        for (int kt = 0; kt < 8; ++kt) {
            const int j0 = kt * 64;
#pragma unroll
            for (int q = 0; q < 2; ++q) gload16(srcA[q] + offA + j0, (char*)a_lds + dstA[q]);
#pragma unroll
            for (int q = 0; q < 4; ++q) gload16(srcB[q] + offB + j0, (char*)b_lds + dstB[q]);
            __syncthreads();
#pragma unroll
            for (int ks = 0; ks < 2; ++ks) {
                bf16x8 af[2], bf[4];
#pragma unroll
                for (int fn = 0; fn < 2; ++fn) {
                    const int ra = wn * 32 + fn * 16 + l15;
                    af[fn] = *(const bf16x8*)((const char*)a_lds + ra * 128 + (((ks * 4 + lgrp) ^ (ra & 7)) * 16));
                }
#pragma unroll
                for (int fi = 0; fi < 4; ++fi) {
                    const int rb = wi * 64 + fi * 16 + l15;
                    bf[fi] = *(const bf16x8*)((const char*)b_lds + rb * 128 + (((ks * 4 + lgrp) ^ (rb & 7)) * 16));
                }
#pragma unroll
                for (int fn = 0; fn < 2; ++fn)
#pragma unroll
                    for (int fi = 0; fi < 4; ++fi)
                        acc[fn][fi] = __builtin_amdgcn_mfma_f32_16x16x32_bf16(af[fn], bf[fi], acc[fn][fi], 0, 0, 0);
            }
            __syncthreads();
        }

        // gate + pack -> g_lds[s=wn][i][d] (72B rows; banks conflict-free)
#pragma unroll
        for (int fn = 0; fn < 2; ++fn) {
            const int d0 = fn * 16 + lgrp * 4;
#pragma unroll
            for (int fi = 0; fi < 4; ++fi) {
                const int i = wi * 64 + fi * 16 + l15;
                const uint2 uu = gpre[fn][fi];
                const float g0 = bf2f(uu.x & 0xFFFFu), g1 = bf2f(uu.x >> 16);
                const float g2 = bf2f(uu.y & 0xFFFFu), g3 = bf2f(uu.y >> 16);
                uint2 o;
                o.x = (unsigned)f2bf(acc[fn][fi][0] * g0) | ((unsigned)f2bf(acc[fn][fi][1] * g1) << 16);
                o.y = (unsigned)f2bf(acc[fn][fi][2] * g2) | ((unsigned)f2bf(acc[fn][fi][3] * g3) << 16);
                *(uint2*)(g_lds + (wn * 128 + i) * GROW + d0 * 2) = o;
            }
        }
        __syncthreads();

        bf16x8 bw[4];
#pragma unroll
        for (int mf = 0; mf < 4; ++mf)
            bw[mf] = *(const bf16x8*)(WoutT + (mf * 16 + l15) * 256 + h * 32 + lgrp * 8);
#pragma unroll
        for (int s = 0; s < 2; ++s) {
#pragma unroll
            for (int f = 0; f < 2; ++f) {
                const int ra = w * 32 + f * 16 + l15;
                const bf16x8 af = *(const bf16x8*)(g_lds + (s * 128 + ra) * GROW + lgrp * 16);
#pragma unroll
                for (int mf = 0; mf < 4; ++mf)
                    oacc[s][f][mf] = __builtin_amdgcn_mfma_f32_16x16x32_bf16(af, bw[mf], oacc[s][f][mf], 0, 0, 0);
            }
        }
        __syncthreads();
    }

#pragma unroll
    for (int s = 0; s < 2; ++s)
#pragma unroll
        for (int f = 0; f < 2; ++f)
#pragma unroll
            for (int mf = 0; mf < 4; ++mf)
#pragma unroll
                for (int r = 0; r < 4; ++r) {
                    const size_t row = (size_t)(s0 + s) * 512 + i0 + w * 32 + f * 16 + lgrp * 4 + r;
                    out[row * 64 + mf * 16 + l15] = oacc[s][f][mf][r];
                }
}

extern "C" void kernel_launch(void* const* d_in, const int* in_sizes, int n_in,
                              void* d_out, int out_size, void* d_ws, size_t ws_size,
                              hipStream_t stream) {
    (void)in_sizes; (void)n_in; (void)out_size; (void)ws_size;
    const float* msa       = (const float*)d_in[0];
    const float* pair      = (const float*)d_in[1];
    const float* ln_msa_g  = (const float*)d_in[2];
    const float* ln_msa_b  = (const float*)d_in[3];
    const float* W_vg      = (const float*)d_in[4];
    const float* ln_pair_g = (const float*)d_in[5];
    const float* ln_pair_b = (const float*)d_in[6];
    const float* W_pair    = (const float*)d_in[7];
    const float* W_out     = (const float*)d_in[8];
    float* out = (float*)d_out;

    char* ws = (char*)d_ws;
    size_t off = 0;
    unsigned short* VT    = (unsigned short*)(ws + off); off += (size_t)ROWS * C * 2;  // 67.1 MB
    unsigned short* G     = (unsigned short*)(ws + off); off += (size_t)ROWS * C * 2;  // 67.1 MB
    unsigned short* Wt    = (unsigned short*)(ws + off); off += (size_t)H * N * N * 2; // 4.2 MB
    unsigned short* biasb = (unsigned short*)(ws + off); off += (size_t)N * N * 8 * 2; // 4.2 MB
    unsigned short* WTvg  = (unsigned short*)(ws + off); off += 512 * 64 * 2;          // 64 KB
    float*          biasvg = (float*)(ws + off); off += 512 * 4;                       // 2 KB
    unsigned short* WoutT = (unsigned short*)(ws + off); off += 64 * 256 * 2;          // 32 KB
    float*          Wg    = (float*)(ws + off); off += 128 * 8 * 4;                    // 4 KB
    float*          sgcb  = (float*)(ws + off); off += 16 * 4;

    k0_prep<<<4, 256, 0, stream>>>(W_vg, ln_msa_g, ln_msa_b, W_out, ln_pair_g, ln_pair_b, W_pair,
                                   WTvg, biasvg, WoutT, Wg, sgcb);
    k2a_bias<<<4096, 256, 0, stream>>>(pair, Wg, sgcb, biasb);
    k2b_softmax<<<512, 512, 0, stream>>>(biasb, Wt);
    k1_vg_mfma<<<512, 512, 0, stream>>>(msa, WTvg, biasvg, VT, G);
    k3_fused_out<<<512, 256, 0, stream>>>(Wt, VT, G, WoutT, out);
}